// Round 11
// baseline (297.197 us; speedup 1.0000x reference)
//
#include <hip/hip_runtime.h>
#include <hip/hip_bf16.h>

#define N_NODES 65536
#define N_EDGES 524288

typedef __attribute__((ext_vector_type(8))) short bf16x8;
typedef __attribute__((ext_vector_type(4))) float f32x4;

__device__ __forceinline__ float bf2f(unsigned short u) {
    union { unsigned int i; float f; } v;
    v.i = ((unsigned int)u) << 16;
    return v.f;
}
__device__ __forceinline__ unsigned short f2bf(float f) {
    union { float f; unsigned int i; } v;
    v.f = f;
    unsigned int r = v.i + 0x7fff + ((v.i >> 16) & 1);  // round-to-nearest-even
    return (unsigned short)(r >> 16);
}

// ---------------- init: deg=1 (self-loop), cnt=0, logits=0 --------------------
__global__ void init_k(float* __restrict__ deg, int* __restrict__ cnt,
                       float* __restrict__ logits) {
    int i = blockIdx.x * 256 + threadIdx.x;
    deg[i] = 1.0f;
    cnt[i] = 0;
    if (i < 512) logits[i] = 0.0f;
}
__global__ void deg_cnt_k(const int* __restrict__ dst, const float* __restrict__ w,
                          float* __restrict__ deg, int* __restrict__ cnt) {
    int e = blockIdx.x * 256 + threadIdx.x;
    int d = dst[e];
    atomicAdd(&deg[d], w[e]);
    atomicAdd(&cnt[d], 1);
}

// ------- hierarchical exclusive scan of cnt[65536] -> rp, cursor, dinv --------
__global__ __launch_bounds__(256) void scan1_k(const int* __restrict__ cnt,
                                               int* __restrict__ rp,
                                               int* __restrict__ bsum) {
    __shared__ int s[256];
    int t = threadIdx.x, g = blockIdx.x * 256 + t;
    int v = cnt[g];
    s[t] = v;
    __syncthreads();
    for (int d = 1; d < 256; d <<= 1) {
        int u = (t >= d) ? s[t - d] : 0;
        __syncthreads();
        s[t] += u;
        __syncthreads();
    }
    rp[g] = s[t] - v;
    if (t == 255) bsum[blockIdx.x] = s[255];
}
__global__ __launch_bounds__(256) void scan2_k(int* __restrict__ bsum,
                                               int* __restrict__ rp) {
    __shared__ int s[256];
    int t = threadIdx.x;
    int v = bsum[t];
    s[t] = v;
    __syncthreads();
    for (int d = 1; d < 256; d <<= 1) {
        int u = (t >= d) ? s[t - d] : 0;
        __syncthreads();
        s[t] += u;
        __syncthreads();
    }
    bsum[t] = s[t] - v;
    if (t == 255) rp[65536] = s[255];
}
__global__ __launch_bounds__(256) void scan3_k(int* __restrict__ rp,
                                               const int* __restrict__ bsum,
                                               int* __restrict__ cursor,
                                               const float* __restrict__ deg,
                                               float* __restrict__ dinv) {
    int t = threadIdx.x, g = blockIdx.x * 256 + t;
    int r = rp[g] + bsum[blockIdx.x];
    rp[g] = r;
    cursor[g] = r;
    dinv[g] = rsqrtf(deg[g]);
}

// ------- scatter edges into dst-sorted CSR order, packed (src, coef) ----------
__global__ void scatter_k(const int* __restrict__ src, const int* __restrict__ dst,
                          const float* __restrict__ w, const float* __restrict__ dinv,
                          int* __restrict__ cursor, uint2* __restrict__ ep) {
    int e = blockIdx.x * 256 + threadIdx.x;
    int s = src[e], d = dst[e];
    int pos = atomicAdd(&cursor[d], 1);
    uint2 p;
    p.x = (unsigned int)s;
    p.y = __float_as_uint(dinv[s] * w[e] * dinv[d]);
    ep[pos] = p;
}

// -------- merged weight/x prep: f2b(x) | f2b(wc1) | f2b(wc2) | wcomb ----------
__global__ void prep_k(const float* __restrict__ x, __hip_bfloat16* __restrict__ xbf,
                       const float* __restrict__ wc1, __hip_bfloat16* __restrict__ wc1bf,
                       const float* __restrict__ wc2, __hip_bfloat16* __restrict__ wc2bf,
                       const float* __restrict__ w1, const float* __restrict__ wg,
                       __hip_bfloat16* __restrict__ WT) {
    int bid = blockIdx.x;
    if (bid < 9344) {
        const float* in;
        __hip_bfloat16* outp;
        int i;
        if (bid < 8192) { in = x; outp = xbf; i = bid * 1024 + threadIdx.x * 4; }
        else if (bid < 9216) { in = wc1; outp = wc1bf; i = (bid - 8192) * 1024 + threadIdx.x * 4; }
        else { in = wc2; outp = wc2bf; i = (bid - 9216) * 1024 + threadIdx.x * 4; }
        float4 v = *(const float4*)(in + i);
        alignas(8) __hip_bfloat16 tmp[4] = {__float2bfloat16(v.x), __float2bfloat16(v.y),
                                            __float2bfloat16(v.z), __float2bfloat16(v.w)};
        *(ushort4*)((unsigned short*)outp + i) = *(const ushort4*)tmp;
    } else {
        int t = (bid - 9344) * 256 + threadIdx.x;
        int f = t >> 7, c = t & 127;
        float s = 0.f;
#pragma unroll 8
        for (int m = 0; m < 128; ++m) s += w1[c * 128 + m] * wg[m * 512 + f];
        WT[t] = __float2bfloat16(s);
    }
}

// ---------------- gather SpMM, 4-deep ILP pipeline -----------------------------
__global__ __launch_bounds__(256) void gather_k(const int* __restrict__ rp,
                                                const uint2* __restrict__ ep,
                                                const unsigned short* __restrict__ xbf,
                                                const float* __restrict__ dinv,
                                                __hip_bfloat16* __restrict__ ybf) {
    int n = (blockIdx.x * 256 + threadIdx.x) >> 6;
    int lane = threadIdx.x & 63;
    int beg = rp[n], end = rp[n + 1];
    float di = dinv[n];
    float accx, accy;
    {
        unsigned int u = *(const unsigned int*)(xbf + (size_t)n * 128 + lane * 2);
        float c = di * di;
        accx = c * bf2f((unsigned short)(u & 0xffff));
        accy = c * bf2f((unsigned short)(u >> 16));
    }
    int i = beg;
    for (; i + 4 <= end; i += 4) {
        uint2 p0 = ep[i], p1 = ep[i + 1], p2 = ep[i + 2], p3 = ep[i + 3];
        unsigned int u0 = *(const unsigned int*)(xbf + (size_t)p0.x * 128 + lane * 2);
        unsigned int u1 = *(const unsigned int*)(xbf + (size_t)p1.x * 128 + lane * 2);
        unsigned int u2 = *(const unsigned int*)(xbf + (size_t)p2.x * 128 + lane * 2);
        unsigned int u3 = *(const unsigned int*)(xbf + (size_t)p3.x * 128 + lane * 2);
        float c0 = __uint_as_float(p0.y), c1 = __uint_as_float(p1.y);
        float c2 = __uint_as_float(p2.y), c3 = __uint_as_float(p3.y);
        accx += c0 * bf2f((unsigned short)(u0 & 0xffff));
        accy += c0 * bf2f((unsigned short)(u0 >> 16));
        accx += c1 * bf2f((unsigned short)(u1 & 0xffff));
        accy += c1 * bf2f((unsigned short)(u1 >> 16));
        accx += c2 * bf2f((unsigned short)(u2 & 0xffff));
        accy += c2 * bf2f((unsigned short)(u2 >> 16));
        accx += c3 * bf2f((unsigned short)(u3 & 0xffff));
        accy += c3 * bf2f((unsigned short)(u3 >> 16));
    }
    for (; i < end; ++i) {
        uint2 p = ep[i];
        unsigned int u = *(const unsigned int*)(xbf + (size_t)p.x * 128 + lane * 2);
        float c = __uint_as_float(p.y);
        accx += c * bf2f((unsigned short)(u & 0xffff));
        accy += c * bf2f((unsigned short)(u >> 16));
    }
    alignas(4) __hip_bfloat16 o[2] = {__float2bfloat16(accx), __float2bfloat16(accy)};
    *(unsigned int*)((unsigned short*)ybf + (size_t)n * 128 + lane * 2) =
        *(const unsigned int*)o;
}

// ---------------- async global -> LDS, 16B per lane ---------------------------
__device__ __forceinline__ void gll16(const void* g, void* l) {
    __builtin_amdgcn_global_load_lds(
        (const __attribute__((address_space(1))) void*)g,
        (__attribute__((address_space(3))) void*)l, 16, 0, 0);
}

// ---------------- bf16 MFMA GEMM: A via LDS (3-buf), B DIRECT from L2 ---------
// C = act(A @ B^T + bias). B (weights, N x K, L2-resident) is loaded straight
// into registers with 1-step-ahead prefetch -- halves the LDS pipe load that
// bounds the barrier window. A staged via gll16, XOR-swizzled slot^((row>>1)&3)
// (both sides). Counted vmcnt keeps 2 A-stages + B prefetch in flight.
// SWAPPED-OPERAND mfma: lane holds 4 consecutive output cols of one row.
// ACT: 1 relu, 2 tanh(fast). OUT_MODE: 1 bf16 rm, 2 bf16 permute, 3 final dot.
// SWIZ_NTX>0: XCD-chunked 1D grid. Requires nk = K/32 >= 3.
template <int ACT, int OUT_MODE, int SWIZ_NTX>
__global__ __launch_bounds__(256) void gemm_mfma_k(
    const __hip_bfloat16* __restrict__ A, const __hip_bfloat16* __restrict__ B,
    const float* __restrict__ bias, void* __restrict__ Cout,
    const float* __restrict__ wlin, int M, int N, int K) {
    __shared__ char lds[24576];  // 3 bufs x A-tile 8KB

    const int tid = threadIdx.x;
    const int lane = tid & 63, wid = tid >> 6;
    int bx, by;
    if (SWIZ_NTX > 0) {
        int orig = blockIdx.x;
        int per = gridDim.x / (8 * SWIZ_NTX);
        int xcd = orig & 7, k = orig >> 3;
        by = xcd * per + k / SWIZ_NTX;
        bx = k % SWIZ_NTX;
    } else {
        bx = blockIdx.x;
        by = blockIdx.y;
    }
    const int bm = by * 128, bn = bx * 128;
    const int wr = wid >> 1, wc = wid & 1;

    // A staging: row srow, physical 16B slot (lane&3); source col pre-swizzled
    // so physical slot p at row r holds logical col p ^ ((r>>1)&3).
    const int srow = wid * 16 + (lane >> 2);
    const int skcol = (((lane & 3) ^ ((lane >> 3) & 3))) * 8;  // elements
    const __hip_bfloat16* Abase = A + (size_t)(bm + srow) * K + skcol;
    const int ldso = wid * 1024;

    // B direct: per-lane row pointers for the 4 fragments
    const __hip_bfloat16* Bp[4];
#pragma unroll
    for (int j = 0; j < 4; ++j)
        Bp[j] = B + (size_t)(bn + wc * 64 + j * 16 + (lane & 15)) * K + (lane >> 4) * 8;

    f32x4 acc[4][4] = {};

    const int lrow = lane & 15;
    // read: logical slot (lane>>4) at rows r with (r>>1)&3 == (lane>>1)&3
    const int lkb = (((lane >> 4) ^ ((lane >> 1) & 3)) << 4);
    const int nk = K >> 5;

    auto stageA = [&](int buf, int kt) {
        char* la = lds + buf * 8192;
        gll16(Abase + kt * 32,                  la + ldso);
        gll16(Abase + kt * 32 + (size_t)64 * K, la + 4096 + ldso);
    };

    // prologue -- fence pins issue order so the vmcnt counts below are exact:
    // A(0):2, A(1):2, then B(0):4.
    stageA(0, 0);
    stageA(1, 1);
    asm volatile("" ::: "memory");
    bf16x8 bcur[4], bnext[4];
#pragma unroll
    for (int j = 0; j < 4; ++j) bcur[j] = *(const bf16x8*)(Bp[j]);

    for (int kt = 0; kt < nk; ++kt) {
        if (kt + 2 < nk) stageA((kt + 2) % 3, kt + 2);
        if (kt + 1 < nk) {
#pragma unroll
            for (int j = 0; j < 4; ++j)
                bnext[j] = *(const bf16x8*)(Bp[j] + (kt + 1) * 32);
        }
        // VMEM ops issued after A(kt)'s gll16 pair:
        //   kt==0:           A(1)2 + B(0)4 + A(2)2 + B(1)4            = 12
        //   1<=kt<=nk-3:     B(kt-1)4 + A(kt+1)2 + B(kt)4 + A(kt+2)2 + B(kt+1)4 = 16
        //   kt==nk-2:        B(kt-1)4 + A(kt+1)2 + B(kt)4 + B(kt+1)4  = 14
        //   kt==nk-1:        B(kt-1)4 + B(kt)4                        = 8
        if (kt == 0)          asm volatile("s_waitcnt vmcnt(12)" ::: "memory");
        else if (kt + 2 < nk) asm volatile("s_waitcnt vmcnt(16)" ::: "memory");
        else if (kt + 1 < nk) asm volatile("s_waitcnt vmcnt(14)" ::: "memory");
        else                  asm volatile("s_waitcnt vmcnt(8)"  ::: "memory");
        __builtin_amdgcn_s_barrier();      // all waves' A(kt) now in LDS
        asm volatile("" ::: "memory");

        const char* la = lds + (kt % 3) * 8192;
        bf16x8 af[4];
#pragma unroll
        for (int i = 0; i < 4; ++i)
            af[i] = *(const bf16x8*)(la + (wr * 64 + i * 16 + lrow) * 64 + lkb);
        __builtin_amdgcn_s_setprio(1);
#pragma unroll
        for (int i = 0; i < 4; ++i)
#pragma unroll
            for (int j = 0; j < 4; ++j)
                acc[i][j] = __builtin_amdgcn_mfma_f32_16x16x32_bf16(
                    bcur[j], af[i], acc[i][j], 0, 0, 0);  // SWAPPED operands
        __builtin_amdgcn_s_setprio(0);
        asm volatile("" ::: "memory");
        __builtin_amdgcn_s_barrier();      // buf kt free for overwrite
#pragma unroll
        for (int j = 0; j < 4; ++j) bcur[j] = bnext[j];
    }

    const int l15 = lane & 15, lhi = lane >> 4;

    if (OUT_MODE == 3) {
        // row m = bm+wr*64+i*16+l15 ; col p = bn+wc*64+j*16+lhi*4+r
        float p0 = 0.f, p1 = 0.f;
#pragma unroll
        for (int i = 0; i < 4; ++i) {
            int e = (i & 1) * 16 + l15;  // m & 31
#pragma unroll
            for (int j = 0; j < 4; ++j) {
                int n = bn + wc * 64 + j * 16 + lhi * 4;
                float4 bv = *(const float4*)(bias + n);
#pragma unroll
                for (int r = 0; r < 4; ++r) {
                    float v = fmaxf(acc[i][j][r] + ((const float*)&bv)[r], 0.f);
                    float wl = wlin[(n + r) * 32 + e];
                    if (i < 2) p0 += v * wl; else p1 += v * wl;
                }
            }
        }
#pragma unroll
        for (int off = 32; off > 0; off >>= 1) {
            p0 += __shfl_down(p0, off, 64);
            p1 += __shfl_down(p1, off, 64);
        }
        if (lane == 0) {
            int g = (bm >> 5) + wr * 2;
            atomicAdd(&((float*)Cout)[g], p0);
            atomicAdd(&((float*)Cout)[g + 1], p1);
        }
        return;
    }

#pragma unroll
    for (int i = 0; i < 4; ++i) {
        int m = bm + wr * 64 + i * 16 + l15;
#pragma unroll
        for (int j = 0; j < 4; ++j) {
            int n = bn + wc * 64 + j * 16 + lhi * 4;
            float4 bv = *(const float4*)(bias + n);
            ushort4 o;
#pragma unroll
            for (int r = 0; r < 4; ++r) {
                float v = acc[i][j][r] + ((const float*)&bv)[r];
                if (ACT == 1) v = fmaxf(v, 0.f);
                if (ACT == 2) v = 1.0f - 2.0f / (__expf(2.0f * v) + 1.0f);
                ((unsigned short*)&o)[r] = f2bf(v);
            }
            if (OUT_MODE == 1) {
                *(ushort4*)((unsigned short*)Cout + (size_t)m * N + n) = o;
            } else {
                size_t prow = (size_t)(((m >> 7) << 5) | (m & 31));
                size_t idx = prow * 2048 + (size_t)(((m >> 5) & 3) * 512 + n);
                *(ushort4*)((unsigned short*)Cout + idx) = o;
            }
        }
    }
}

// ---------------- sigmoid over 512 graph logits --------------------------------
__global__ void sigmoid_k(const float* __restrict__ logits,
                          const float* __restrict__ blin, float* __restrict__ out) {
    int b = blockIdx.x * 256 + threadIdx.x;
    out[b] = 1.0f / (1.0f + expf(-(logits[b] + blin[0])));
}

extern "C" void kernel_launch(void* const* d_in, const int* in_sizes, int n_in,
                              void* d_out, int out_size, void* d_ws, size_t ws_size,
                              hipStream_t stream) {
    const float* x    = (const float*)d_in[0];
    const float* eattr= (const float*)d_in[1];
    const float* w1   = (const float*)d_in[2];
    const float* wg   = (const float*)d_in[3];
    const float* bg   = (const float*)d_in[4];
    const float* wc1  = (const float*)d_in[5];
    const float* bc1  = (const float*)d_in[6];
    const float* wc2  = (const float*)d_in[7];
    const float* bc2  = (const float*)d_in[8];
    const float* wlin = (const float*)d_in[9];
    const float* blin = (const float*)d_in[10];
    const int*   ei   = (const int*)d_in[11];
    const int* esrc = ei;
    const int* edst = ei + N_EDGES;
    float* out = (float*)d_out;

    // workspace layout (bytes, 16B aligned)
    char* ws = (char*)d_ws;
    float*          dinv   = (float*)(ws + 0);          // 262144
    int*            cnt    = (int*)(ws + 262144);       // 262144
    int*            rp     = (int*)(ws + 524288);       // 262160 (65537 ints)
    int*            cursor = (int*)(ws + 786688);       // 262144
    uint2*          ep     = (uint2*)(ws + 1048832);    // 4194304
    __hip_bfloat16* WTbf   = (__hip_bfloat16*)(ws + 5243136);   // 131072
    __hip_bfloat16* ybf    = (__hip_bfloat16*)(ws + 5374208);   // 16777216
    __hip_bfloat16* V      = (__hip_bfloat16*)(ws + 22151424);  // 67108864
    __hip_bfloat16* act1   = (__hip_bfloat16*)(ws + 89260288);  // 16777216
    __hip_bfloat16* wc1bf  = (__hip_bfloat16*)(ws + 106037504); // 2097152
    __hip_bfloat16* wc2bf  = (__hip_bfloat16*)(ws + 108134656); // 262144
    __hip_bfloat16* xbf    = (__hip_bfloat16*)(ws + 108396800); // 16777216
    float*          logits = (float*)(ws + 125174016);  // 2048
    int*            bsum   = (int*)(ws + 125176064);    // 1024
    if (ws_size < (size_t)125177088) return;

    // 1) init
    init_k<<<N_NODES / 256, 256, 0, stream>>>(dinv, cnt, logits);

    // 2) degree + in-degree counts
    deg_cnt_k<<<N_EDGES / 256, 256, 0, stream>>>(edst, eattr, dinv, cnt);

    // 3) hierarchical scan
    scan1_k<<<256, 256, 0, stream>>>(cnt, rp, bsum);
    scan2_k<<<1, 256, 0, stream>>>(bsum, rp);
    scan3_k<<<256, 256, 0, stream>>>(rp, bsum, cursor, dinv, dinv);

    // 4) scatter edges into CSR, packed 8B records
    scatter_k<<<N_EDGES / 256, 256, 0, stream>>>(esrc, edst, eattr, dinv,
                                                 cursor, ep);

    // 5) merged prep
    prep_k<<<9600, 256, 0, stream>>>(x, xbf, wc1, wc1bf, wc2, wc2bf, w1, wg, WTbf);

    // 6) gather SpMM on bf16 x -> ybf (4-deep ILP)
    gather_k<<<N_NODES / 4, 256, 0, stream>>>(rp, ep,
                                              (const unsigned short*)xbf, dinv, ybf);

    // 7) h2 = tanh(y @ W_comb + b_gcn) -> V (bf16, rearranged layout)
    gemm_mfma_k<2, 2, 0><<<dim3(4, 512), 256, 0, stream>>>(
        ybf, WTbf, bg, V, nullptr, 65536, 512, 128);

    // 8) cnn1: act1 = relu(V @ wc1^T + bc1), XCD-swizzled 1D grid
    gemm_mfma_k<1, 1, 4><<<512, 256, 0, stream>>>(
        V, wc1bf, bc1, act1, nullptr, 16384, 512, 2048);

    // 9) cnn2 + final dot fused
    gemm_mfma_k<1, 3, 0><<<dim3(2, 128), 256, 0, stream>>>(
        act1, wc2bf, bc2, logits, wlin, 16384, 256, 512);

    // 10) sigmoid
    sigmoid_k<<<2, 256, 0, stream>>>(logits, blin, out);
}

// Round 12
// 247.417 us; speedup vs baseline: 1.2012x; 1.2012x over previous
//
#include <hip/hip_runtime.h>
#include <hip/hip_bf16.h>

#define N_NODES 65536
#define N_EDGES 524288

typedef __attribute__((ext_vector_type(8))) short bf16x8;
typedef __attribute__((ext_vector_type(4))) float f32x4;

__device__ __forceinline__ float bf2f(unsigned short u) {
    union { unsigned int i; float f; } v;
    v.i = ((unsigned int)u) << 16;
    return v.f;
}
__device__ __forceinline__ unsigned short f2bf(float f) {
    union { float f; unsigned int i; } v;
    v.f = f;
    unsigned int r = v.i + 0x7fff + ((v.i >> 16) & 1);  // round-to-nearest-even
    return (unsigned short)(r >> 16);
}

// ---------------- init: deg=1 (self-loop), cnt=0, logits=0 --------------------
__global__ void init_k(float* __restrict__ deg, int* __restrict__ cnt,
                       float* __restrict__ logits) {
    int i = blockIdx.x * 256 + threadIdx.x;
    deg[i] = 1.0f;
    cnt[i] = 0;
    if (i < 512) logits[i] = 0.0f;
}
__global__ void deg_cnt_k(const int* __restrict__ dst, const float* __restrict__ w,
                          float* __restrict__ deg, int* __restrict__ cnt) {
    int e = blockIdx.x * 256 + threadIdx.x;
    int d = dst[e];
    atomicAdd(&deg[d], w[e]);
    atomicAdd(&cnt[d], 1);
}

// ------- hierarchical exclusive scan of cnt[65536] -> rp, cursor, dinv --------
__global__ __launch_bounds__(256) void scan1_k(const int* __restrict__ cnt,
                                               int* __restrict__ rp,
                                               int* __restrict__ bsum) {
    __shared__ int s[256];
    int t = threadIdx.x, g = blockIdx.x * 256 + t;
    int v = cnt[g];
    s[t] = v;
    __syncthreads();
    for (int d = 1; d < 256; d <<= 1) {
        int u = (t >= d) ? s[t - d] : 0;
        __syncthreads();
        s[t] += u;
        __syncthreads();
    }
    rp[g] = s[t] - v;
    if (t == 255) bsum[blockIdx.x] = s[255];
}
__global__ __launch_bounds__(256) void scan2_k(int* __restrict__ bsum,
                                               int* __restrict__ rp) {
    __shared__ int s[256];
    int t = threadIdx.x;
    int v = bsum[t];
    s[t] = v;
    __syncthreads();
    for (int d = 1; d < 256; d <<= 1) {
        int u = (t >= d) ? s[t - d] : 0;
        __syncthreads();
        s[t] += u;
        __syncthreads();
    }
    bsum[t] = s[t] - v;
    if (t == 255) rp[65536] = s[255];
}
__global__ __launch_bounds__(256) void scan3_k(int* __restrict__ rp,
                                               const int* __restrict__ bsum,
                                               int* __restrict__ cursor,
                                               const float* __restrict__ deg,
                                               float* __restrict__ dinv) {
    int t = threadIdx.x, g = blockIdx.x * 256 + t;
    int r = rp[g] + bsum[blockIdx.x];
    rp[g] = r;
    cursor[g] = r;
    dinv[g] = rsqrtf(deg[g]);
}

// ------- scatter edges into dst-sorted CSR order, packed (src, coef) ----------
__global__ void scatter_k(const int* __restrict__ src, const int* __restrict__ dst,
                          const float* __restrict__ w, const float* __restrict__ dinv,
                          int* __restrict__ cursor, uint2* __restrict__ ep) {
    int e = blockIdx.x * 256 + threadIdx.x;
    int s = src[e], d = dst[e];
    int pos = atomicAdd(&cursor[d], 1);
    uint2 p;
    p.x = (unsigned int)s;
    p.y = __float_as_uint(dinv[s] * w[e] * dinv[d]);
    ep[pos] = p;
}

// -------- merged weight/x prep: f2b(x) | f2b(wc1) | f2b(wc2) | wcomb ----------
__global__ void prep_k(const float* __restrict__ x, __hip_bfloat16* __restrict__ xbf,
                       const float* __restrict__ wc1, __hip_bfloat16* __restrict__ wc1bf,
                       const float* __restrict__ wc2, __hip_bfloat16* __restrict__ wc2bf,
                       const float* __restrict__ w1, const float* __restrict__ wg,
                       __hip_bfloat16* __restrict__ WT) {
    int bid = blockIdx.x;
    if (bid < 9344) {
        const float* in;
        __hip_bfloat16* outp;
        int i;
        if (bid < 8192) { in = x; outp = xbf; i = bid * 1024 + threadIdx.x * 4; }
        else if (bid < 9216) { in = wc1; outp = wc1bf; i = (bid - 8192) * 1024 + threadIdx.x * 4; }
        else { in = wc2; outp = wc2bf; i = (bid - 9216) * 1024 + threadIdx.x * 4; }
        float4 v = *(const float4*)(in + i);
        alignas(8) __hip_bfloat16 tmp[4] = {__float2bfloat16(v.x), __float2bfloat16(v.y),
                                            __float2bfloat16(v.z), __float2bfloat16(v.w)};
        *(ushort4*)((unsigned short*)outp + i) = *(const ushort4*)tmp;
    } else {
        int t = (bid - 9344) * 256 + threadIdx.x;
        int f = t >> 7, c = t & 127;
        float s = 0.f;
#pragma unroll 8
        for (int m = 0; m < 128; ++m) s += w1[c * 128 + m] * wg[m * 512 + f];
        WT[t] = __float2bfloat16(s);
    }
}

// ---------------- gather SpMM, 4-deep ILP pipeline -----------------------------
__global__ __launch_bounds__(256) void gather_k(const int* __restrict__ rp,
                                                const uint2* __restrict__ ep,
                                                const unsigned short* __restrict__ xbf,
                                                const float* __restrict__ dinv,
                                                __hip_bfloat16* __restrict__ ybf) {
    int n = (blockIdx.x * 256 + threadIdx.x) >> 6;
    int lane = threadIdx.x & 63;
    int beg = rp[n], end = rp[n + 1];
    float di = dinv[n];
    float accx, accy;
    {
        unsigned int u = *(const unsigned int*)(xbf + (size_t)n * 128 + lane * 2);
        float c = di * di;
        accx = c * bf2f((unsigned short)(u & 0xffff));
        accy = c * bf2f((unsigned short)(u >> 16));
    }
    int i = beg;
    for (; i + 4 <= end; i += 4) {
        uint2 p0 = ep[i], p1 = ep[i + 1], p2 = ep[i + 2], p3 = ep[i + 3];
        unsigned int u0 = *(const unsigned int*)(xbf + (size_t)p0.x * 128 + lane * 2);
        unsigned int u1 = *(const unsigned int*)(xbf + (size_t)p1.x * 128 + lane * 2);
        unsigned int u2 = *(const unsigned int*)(xbf + (size_t)p2.x * 128 + lane * 2);
        unsigned int u3 = *(const unsigned int*)(xbf + (size_t)p3.x * 128 + lane * 2);
        float c0 = __uint_as_float(p0.y), c1 = __uint_as_float(p1.y);
        float c2 = __uint_as_float(p2.y), c3 = __uint_as_float(p3.y);
        accx += c0 * bf2f((unsigned short)(u0 & 0xffff));
        accy += c0 * bf2f((unsigned short)(u0 >> 16));
        accx += c1 * bf2f((unsigned short)(u1 & 0xffff));
        accy += c1 * bf2f((unsigned short)(u1 >> 16));
        accx += c2 * bf2f((unsigned short)(u2 & 0xffff));
        accy += c2 * bf2f((unsigned short)(u2 >> 16));
        accx += c3 * bf2f((unsigned short)(u3 & 0xffff));
        accy += c3 * bf2f((unsigned short)(u3 >> 16));
    }
    for (; i < end; ++i) {
        uint2 p = ep[i];
        unsigned int u = *(const unsigned int*)(xbf + (size_t)p.x * 128 + lane * 2);
        float c = __uint_as_float(p.y);
        accx += c * bf2f((unsigned short)(u & 0xffff));
        accy += c * bf2f((unsigned short)(u >> 16));
    }
    alignas(4) __hip_bfloat16 o[2] = {__float2bfloat16(accx), __float2bfloat16(accy)};
    *(unsigned int*)((unsigned short*)ybf + (size_t)n * 128 + lane * 2) =
        *(const unsigned int*)o;
}

// ---------------- async global -> LDS, 16B per lane ---------------------------
__device__ __forceinline__ void gll16(const void* g, void* l) {
    __builtin_amdgcn_global_load_lds(
        (const __attribute__((address_space(1))) void*)g,
        (__attribute__((address_space(3))) void*)l, 16, 0, 0);
}

// ---------------- bf16 MFMA GEMM: 4-buffer, ONE barrier per K-step ------------
// C = act(A @ B^T + bias). A and B both staged via gll16 (coalesced). 2-deep
// prefetch, counted vmcnt (8/4/0), single top barrier: with 4 buffers, the
// stage at iteration kt writes buf (kt+2)%4 = (kt-2)%4, whose reads retired
// before the barrier of kt-1 -- no bottom barrier needed.
// Conflict-free LDS swizzle (verified 0 conflicts in R11): 16B slot p at row r
// holds logical slot p ^ ((r>>1)&3); applied on BOTH sides (pre-swizzled global
// source + swizzled read offset, per-lane constant).
// SWAPPED-OPERAND mfma: lane holds 4 consecutive output cols of one row ->
// 8B ushort4 stores. ACT: 1 relu, 2 tanh(fast). OUT_MODE: 1 bf16 rm,
// 2 bf16 permute, 3 final dot. SWIZ_NTX>0: XCD-chunked 1D grid. nk >= 2.
template <int ACT, int OUT_MODE, int SWIZ_NTX>
__global__ __launch_bounds__(256) void gemm_mfma_k(
    const __hip_bfloat16* __restrict__ A, const __hip_bfloat16* __restrict__ B,
    const float* __restrict__ bias, void* __restrict__ Cout,
    const float* __restrict__ wlin, int M, int N, int K) {
    __shared__ char lds[65536];  // 4 bufs x (A 8KB | B 8KB)

    const int tid = threadIdx.x;
    const int lane = tid & 63, wid = tid >> 6;
    int bx, by;
    if (SWIZ_NTX > 0) {
        int orig = blockIdx.x;
        int per = gridDim.x / (8 * SWIZ_NTX);
        int xcd = orig & 7, k = orig >> 3;
        by = xcd * per + k / SWIZ_NTX;
        bx = k % SWIZ_NTX;
    } else {
        bx = blockIdx.x;
        by = blockIdx.y;
    }
    const int bm = by * 128, bn = bx * 128;
    const int wr = wid >> 1, wc = wid & 1;

    // staging: row srow, physical slot lane&3; source col pre-swizzled so
    // physical slot p at row r holds logical p ^ ((r>>1)&3).
    const int srow = wid * 16 + (lane >> 2);
    const int skcol = (((lane & 3) ^ ((lane >> 3) & 3))) * 8;  // elements
    const __hip_bfloat16* Abase = A + (size_t)(bm + srow) * K + skcol;
    const __hip_bfloat16* Bbase = B + (size_t)(bn + srow) * K + skcol;
    const int ldso = wid * 1024;

    f32x4 acc[4][4] = {};

    const int lrow = lane & 15;
    // read: logical slot (lane>>4) at rows r with (r>>1)&3 == (lane>>1)&3
    const int lkb = (((lane >> 4) ^ ((lane >> 1) & 3)) << 4);
    const int nk = K >> 5;

    auto stage = [&](int buf, int kt) {
        char* la = lds + buf * 16384;
        char* lb = la + 8192;
        gll16(Abase + kt * 32,                  la + ldso);
        gll16(Abase + kt * 32 + (size_t)64 * K, la + 4096 + ldso);
        gll16(Bbase + kt * 32,                  lb + ldso);
        gll16(Bbase + kt * 32 + (size_t)64 * K, lb + 4096 + ldso);
    };

    stage(0, 0);
    if (nk > 1) stage(1, 1);

    for (int kt = 0; kt < nk; ++kt) {
        if (kt + 2 < nk) stage((kt + 2) & 3, kt + 2);
        // outstanding stages beyond kt: 2 (steady) / 1 (kt==nk-2) / 0 (tail)
        if (kt + 2 < nk)      asm volatile("s_waitcnt vmcnt(8)" ::: "memory");
        else if (kt + 1 < nk) asm volatile("s_waitcnt vmcnt(4)" ::: "memory");
        else                  asm volatile("s_waitcnt vmcnt(0)" ::: "memory");
        __builtin_amdgcn_s_barrier();      // all waves' kt-stage now in LDS
        asm volatile("" ::: "memory");

        const char* la = lds + (kt & 3) * 16384;
        const char* lb = la + 8192;
        bf16x8 af[4], bfr[4];
#pragma unroll
        for (int i = 0; i < 4; ++i)
            af[i] = *(const bf16x8*)(la + (wr * 64 + i * 16 + lrow) * 64 + lkb);
#pragma unroll
        for (int j = 0; j < 4; ++j)
            bfr[j] = *(const bf16x8*)(lb + (wc * 64 + j * 16 + lrow) * 64 + lkb);
        __builtin_amdgcn_s_setprio(1);
#pragma unroll
        for (int i = 0; i < 4; ++i)
#pragma unroll
            for (int j = 0; j < 4; ++j)
                acc[i][j] = __builtin_amdgcn_mfma_f32_16x16x32_bf16(
                    bfr[j], af[i], acc[i][j], 0, 0, 0);  // SWAPPED operands
        __builtin_amdgcn_s_setprio(0);
        asm volatile("" ::: "memory");
        // no bottom barrier: 4-buffer rotation makes WAR safe across the
        // single top barrier (stage at kt+1 targets buf (kt+3)&3 = (kt-1)&3,
        // whose reads retired before the kt barrier).
    }

    const int l15 = lane & 15, lhi = lane >> 4;

    if (OUT_MODE == 3) {
        // row m = bm+wr*64+i*16+l15 ; col p = bn+wc*64+j*16+lhi*4+r
        float p0 = 0.f, p1 = 0.f;
#pragma unroll
        for (int i = 0; i < 4; ++i) {
            int e = (i & 1) * 16 + l15;  // m & 31
#pragma unroll
            for (int j = 0; j < 4; ++j) {
                int n = bn + wc * 64 + j * 16 + lhi * 4;
                float4 bv = *(const float4*)(bias + n);
#pragma unroll
                for (int r = 0; r < 4; ++r) {
                    float v = fmaxf(acc[i][j][r] + ((const float*)&bv)[r], 0.f);
                    float wl = wlin[(n + r) * 32 + e];
                    if (i < 2) p0 += v * wl; else p1 += v * wl;
                }
            }
        }
#pragma unroll
        for (int off = 32; off > 0; off >>= 1) {
            p0 += __shfl_down(p0, off, 64);
            p1 += __shfl_down(p1, off, 64);
        }
        if (lane == 0) {
            int g = (bm >> 5) + wr * 2;
            atomicAdd(&((float*)Cout)[g], p0);
            atomicAdd(&((float*)Cout)[g + 1], p1);
        }
        return;
    }

#pragma unroll
    for (int i = 0; i < 4; ++i) {
        int m = bm + wr * 64 + i * 16 + l15;
#pragma unroll
        for (int j = 0; j < 4; ++j) {
            int n = bn + wc * 64 + j * 16 + lhi * 4;
            float4 bv = *(const float4*)(bias + n);
            ushort4 o;
#pragma unroll
            for (int r = 0; r < 4; ++r) {
                float v = acc[i][j][r] + ((const float*)&bv)[r];
                if (ACT == 1) v = fmaxf(v, 0.f);
                if (ACT == 2) v = 1.0f - 2.0f / (__expf(2.0f * v) + 1.0f);
                ((unsigned short*)&o)[r] = f2bf(v);
            }
            if (OUT_MODE == 1) {
                *(ushort4*)((unsigned short*)Cout + (size_t)m * N + n) = o;
            } else {
                size_t prow = (size_t)(((m >> 7) << 5) | (m & 31));
                size_t idx = prow * 2048 + (size_t)(((m >> 5) & 3) * 512 + n);
                *(ushort4*)((unsigned short*)Cout + idx) = o;
            }
        }
    }
}

// ---------------- sigmoid over 512 graph logits --------------------------------
__global__ void sigmoid_k(const float* __restrict__ logits,
                          const float* __restrict__ blin, float* __restrict__ out) {
    int b = blockIdx.x * 256 + threadIdx.x;
    out[b] = 1.0f / (1.0f + expf(-(logits[b] + blin[0])));
}

extern "C" void kernel_launch(void* const* d_in, const int* in_sizes, int n_in,
                              void* d_out, int out_size, void* d_ws, size_t ws_size,
                              hipStream_t stream) {
    const float* x    = (const float*)d_in[0];
    const float* eattr= (const float*)d_in[1];
    const float* w1   = (const float*)d_in[2];
    const float* wg   = (const float*)d_in[3];
    const float* bg   = (const float*)d_in[4];
    const float* wc1  = (const float*)d_in[5];
    const float* bc1  = (const float*)d_in[6];
    const float* wc2  = (const float*)d_in[7];
    const float* bc2  = (const float*)d_in[8];
    const float* wlin = (const float*)d_in[9];
    const float* blin = (const float*)d_in[10];
    const int*   ei   = (const int*)d_in[11];
    const int* esrc = ei;
    const int* edst = ei + N_EDGES;
    float* out = (float*)d_out;

    // workspace layout (bytes, 16B aligned)
    char* ws = (char*)d_ws;
    float*          dinv   = (float*)(ws + 0);          // 262144
    int*            cnt    = (int*)(ws + 262144);       // 262144
    int*            rp     = (int*)(ws + 524288);       // 262160 (65537 ints)
    int*            cursor = (int*)(ws + 786688);       // 262144
    uint2*          ep     = (uint2*)(ws + 1048832);    // 4194304
    __hip_bfloat16* WTbf   = (__hip_bfloat16*)(ws + 5243136);   // 131072
    __hip_bfloat16* ybf    = (__hip_bfloat16*)(ws + 5374208);   // 16777216
    __hip_bfloat16* V      = (__hip_bfloat16*)(ws + 22151424);  // 67108864
    __hip_bfloat16* act1   = (__hip_bfloat16*)(ws + 89260288);  // 16777216
    __hip_bfloat16* wc1bf  = (__hip_bfloat16*)(ws + 106037504); // 2097152
    __hip_bfloat16* wc2bf  = (__hip_bfloat16*)(ws + 108134656); // 262144
    __hip_bfloat16* xbf    = (__hip_bfloat16*)(ws + 108396800); // 16777216
    float*          logits = (float*)(ws + 125174016);  // 2048
    int*            bsum   = (int*)(ws + 125176064);    // 1024
    if (ws_size < (size_t)125177088) return;

    // 1) init
    init_k<<<N_NODES / 256, 256, 0, stream>>>(dinv, cnt, logits);

    // 2) degree + in-degree counts
    deg_cnt_k<<<N_EDGES / 256, 256, 0, stream>>>(edst, eattr, dinv, cnt);

    // 3) hierarchical scan
    scan1_k<<<256, 256, 0, stream>>>(cnt, rp, bsum);
    scan2_k<<<1, 256, 0, stream>>>(bsum, rp);
    scan3_k<<<256, 256, 0, stream>>>(rp, bsum, cursor, dinv, dinv);

    // 4) scatter edges into CSR, packed 8B records
    scatter_k<<<N_EDGES / 256, 256, 0, stream>>>(esrc, edst, eattr, dinv,
                                                 cursor, ep);

    // 5) merged prep
    prep_k<<<9600, 256, 0, stream>>>(x, xbf, wc1, wc1bf, wc2, wc2bf, w1, wg, WTbf);

    // 6) gather SpMM on bf16 x -> ybf (4-deep ILP)
    gather_k<<<N_NODES / 4, 256, 0, stream>>>(rp, ep,
                                              (const unsigned short*)xbf, dinv, ybf);

    // 7) h2 = tanh(y @ W_comb + b_gcn) -> V (bf16, rearranged layout)
    gemm_mfma_k<2, 2, 0><<<dim3(4, 512), 256, 0, stream>>>(
        ybf, WTbf, bg, V, nullptr, 65536, 512, 128);

    // 8) cnn1: act1 = relu(V @ wc1^T + bc1), XCD-swizzled 1D grid
    gemm_mfma_k<1, 1, 4><<<512, 256, 0, stream>>>(
        V, wc1bf, bc1, act1, nullptr, 16384, 512, 2048);

    // 9) cnn2 + final dot fused
    gemm_mfma_k<1, 3, 0><<<dim3(2, 128), 256, 0, stream>>>(
        act1, wc2bf, bc2, logits, wlin, 16384, 256, 512);

    // 10) sigmoid
    sigmoid_k<<<2, 256, 0, stream>>>(logits, blin, out);
}